// Round 2
// baseline (5399.535 us; speedup 1.0000x reference)
//
#include <hip/hip_runtime.h>
#include <hip/hip_bf16.h>
#include <stdint.h>

#define EMBED  512
#define HIDDEN 512
#define VOCAB  32000
#define BATCH  64
#define NPIX   196
#define MAXLEN 32

typedef float f32x4 __attribute__((ext_vector_type(4)));
typedef float f32x2 __attribute__((ext_vector_type(2)));

// ---------- helpers ----------
__device__ __forceinline__ unsigned long long pack_key(float v, int idx) {
    unsigned u = __float_as_uint(v);
    u = (u & 0x80000000u) ? ~u : (u | 0x80000000u);   // monotone sortable map
    return ((unsigned long long)u << 32) | (unsigned)(~(unsigned)idx); // smaller idx wins ties
}

// ---------- init: summary, h0, c0, zero out[:,0,:] ----------
__global__ __launch_bounds__(256) void init_kernel(
    const float* __restrict__ enc,
    const float* __restrict__ W_init_h, const float* __restrict__ b_init_h,
    const float* __restrict__ W_init_c, const float* __restrict__ b_init_c,
    float* __restrict__ h0, float* __restrict__ c0, float* __restrict__ out)
{
    __shared__ __align__(16) float ssum[HIDDEN];
    const int b = blockIdx.x, tid = threadIdx.x;

    // phase A: summary = mean over pixels
    for (int k = tid; k < HIDDEN; k += 256) {
        float s = 0.f;
        const float* p = enc + (size_t)b * NPIX * HIDDEN + k;
        for (int px = 0; px < NPIX; ++px) s += p[(size_t)px * HIDDEN];
        ssum[k] = s * (1.0f / NPIX);
    }
    __syncthreads();

    // phase B: h0 = summary @ W_init_h^T + b, c0 likewise
    for (int j = tid; j < HIDDEN; j += 256) {
        const float4* wh = (const float4*)(W_init_h + (size_t)j * HIDDEN);
        const float4* wc = (const float4*)(W_init_c + (size_t)j * HIDDEN);
        float ah = 0.f, ac = 0.f;
        for (int k4 = 0; k4 < HIDDEN / 4; ++k4) {
            float4 s4 = *(const float4*)&ssum[k4 * 4];
            float4 a = wh[k4], cc = wc[k4];
            ah += s4.x * a.x + s4.y * a.y + s4.z * a.z + s4.w * a.w;
            ac += s4.x * cc.x + s4.y * cc.y + s4.z * cc.z + s4.w * cc.w;
        }
        h0[b * HIDDEN + j] = ah + b_init_h[j];
        c0[b * HIDDEN + j] = ac + b_init_c[j];
    }

    // phase C: zero out[b][0][:]
    f32x4* o4 = (f32x4*)(out + (size_t)b * MAXLEN * VOCAB);
    f32x4 z = {0.f, 0.f, 0.f, 0.f};
    for (int i = tid; i < VOCAB / 4; i += 256) __builtin_nontemporal_store(z, &o4[i]);
}

// ---------- per-step LSTM cell: gates + update ----------
__global__ __launch_bounds__(256) void lstm_step(
    const float* __restrict__ emb,
    const float* __restrict__ W_ih, const float* __restrict__ b_ih,
    const float* __restrict__ W_hh, const float* __restrict__ b_hh,
    const int*  __restrict__ captions,
    const unsigned long long* __restrict__ tok_keys,   // buf[(t-1)&1], valid for t>0
    unsigned long long* __restrict__ reset_keys,       // buf[t&1] -> zero before fc_argmax
    const float* __restrict__ h_in,
    float* __restrict__ h_out,
    float* __restrict__ c_ws,
    int t)
{
    const int tid = threadIdx.x;
    if (blockIdx.x == 0 && tid < BATCH) reset_keys[tid] = 0ull;

    const int u0 = blockIdx.x * 2;          // 256 blocks x 2 hidden units
    const int b = tid >> 2, q = tid & 3;    // 64 batch rows x 4 gate quadrants

    int tok;
    if (t == 0) tok = captions[b * MAXLEN];
    else        tok = (int)(~(unsigned)(tok_keys[b] & 0xffffffffull));

    const float4* x4 = (const float4*)(emb + (size_t)tok * EMBED);
    const float4* h4 = (const float4*)(h_in + b * HIDDEN);
    const int j_0 = q * HIDDEN + u0;        // gate row index (uu = 0)
    const float4* wiA = (const float4*)(W_ih + (size_t)j_0 * EMBED);
    const float4* wiB = wiA + EMBED / 4;
    const float4* whA = (const float4*)(W_hh + (size_t)j_0 * HIDDEN);
    const float4* whB = whA + HIDDEN / 4;

    float a0 = 0.f, a1 = 0.f;
#pragma unroll 4
    for (int k4 = 0; k4 < EMBED / 4; ++k4) {
        float4 xv = x4[k4], hv = h4[k4];
        float4 wA = wiA[k4], wB = wiB[k4], vA = whA[k4], vB = whB[k4];
        a0 += xv.x * wA.x + xv.y * wA.y + xv.z * wA.z + xv.w * wA.w
            + hv.x * vA.x + hv.y * vA.y + hv.z * vA.z + hv.w * vA.w;
        a1 += xv.x * wB.x + xv.y * wB.y + xv.z * wB.z + xv.w * wB.w
            + hv.x * vB.x + hv.y * vB.y + hv.z * vB.z + hv.w * vB.w;
    }
    a0 += b_ih[j_0] + b_hh[j_0];
    a1 += b_ih[j_0 + 1] + b_hh[j_0 + 1];

    const int lane = tid & 63;
    const int base = lane & ~3;
#pragma unroll
    for (int uu = 0; uu < 2; ++uu) {
        float g  = (uu == 0) ? a0 : a1;
        float gi = __shfl(g, base + 0, 64);
        float gf = __shfl(g, base + 1, 64);
        float gg = __shfl(g, base + 2, 64);
        float go = __shfl(g, base + 3, 64);
        if (q == uu) {
            const int u = u0 + uu;
            float i_ = 1.f / (1.f + expf(-gi));
            float f_ = 1.f / (1.f + expf(-gf));
            float o_ = 1.f / (1.f + expf(-go));
            float g_ = tanhf(gg);
            float cv = c_ws[b * HIDDEN + u];
            float c2 = f_ * cv + i_ * g_;
            float h2 = o_ * tanhf(c2);
            c_ws[b * HIDDEN + u]  = c2;
            h_out[b * HIDDEN + u] = h2;
        }
    }
}

// ---------- per-step fc + argmax ----------
// grid 500 blocks: j-tile of 64 columns; block computes C[64][64], K=512.
__global__ __launch_bounds__(256) void fc_argmax(
    const float* __restrict__ h2,
    const float* __restrict__ W_fc,
    const float* __restrict__ b_fc,
    float* __restrict__ out,
    unsigned long long* __restrict__ keys,
    int t)
{
    const int tid = threadIdx.x;
    const int tx = tid & 31, ty = tid >> 5;      // 32 col-groups x 8 row-groups
    const int c0g = blockIdx.x * 64;

    __shared__ __align__(16) float shH[64 * 66];  // transposed [k][row], stride 66
    __shared__ __align__(16) float shW[64 * 66];  // transposed [k][col], stride 66

    float acc[8][2];
#pragma unroll
    for (int r = 0; r < 8; ++r) { acc[r][0] = 0.f; acc[r][1] = 0.f; }

    const float4* h4 = (const float4*)h2;
    const float4* w4 = (const float4*)W_fc + (size_t)c0g * (EMBED / 4);

    for (int kc = 0; kc < 8; ++kc) {
        __syncthreads();
#pragma unroll
        for (int i = 0; i < 4; ++i) {
            const int f4i = tid + 256 * i;
            const int r = f4i >> 4, k4l = f4i & 15;
            float4 hv = h4[r * (EMBED / 4) + kc * 16 + k4l];
            float4 wv = w4[r * (EMBED / 4) + kc * 16 + k4l];
            const int kk = k4l * 4;
            shH[(kk + 0) * 66 + r] = hv.x;
            shH[(kk + 1) * 66 + r] = hv.y;
            shH[(kk + 2) * 66 + r] = hv.z;
            shH[(kk + 3) * 66 + r] = hv.w;
            shW[(kk + 0) * 66 + r] = wv.x;
            shW[(kk + 1) * 66 + r] = wv.y;
            shW[(kk + 2) * 66 + r] = wv.z;
            shW[(kk + 3) * 66 + r] = wv.w;
        }
        __syncthreads();
#pragma unroll 4
        for (int k = 0; k < 64; ++k) {
            const float2 w = *(const float2*)&shW[k * 66 + tx * 2];
            const float* hp = &shH[k * 66 + ty * 8];
#pragma unroll
            for (int rr = 0; rr < 8; ++rr) {
                float hv = hp[rr];
                acc[rr][0] += hv * w.x;
                acc[rr][1] += hv * w.y;
            }
        }
    }

    const int c = c0g + tx * 2;
    const float bb0 = b_fc[c], bb1 = b_fc[c + 1];
#pragma unroll
    for (int rr = 0; rr < 8; ++rr) {
        const int b = ty * 8 + rr;
        float v0 = acc[rr][0] + bb0;
        float v1 = acc[rr][1] + bb1;
        f32x2 st = {v0, v1};
        __builtin_nontemporal_store(st,
            (f32x2*)&out[(size_t)b * MAXLEN * VOCAB + (size_t)(t + 1) * VOCAB + c]);

        unsigned long long k0 = pack_key(v0, c);
        unsigned long long k1 = pack_key(v1, c + 1);
        unsigned long long km = k0 > k1 ? k0 : k1;
#pragma unroll
        for (int m = 16; m >= 1; m >>= 1) {
            unsigned long long o = __shfl_xor(km, m, 64);
            km = km > o ? km : o;
        }
        if (tx == 0) atomicMax(&keys[b], km);
    }
}

extern "C" void kernel_launch(void* const* d_in, const int* in_sizes, int n_in,
                              void* d_out, int out_size, void* d_ws, size_t ws_size,
                              hipStream_t stream) {
    const float* enc       = (const float*)d_in[0];
    const int*   captions  = (const int*)  d_in[1];
    const float* emb       = (const float*)d_in[2];
    const float* W_ih      = (const float*)d_in[3];
    const float* b_ih      = (const float*)d_in[4];
    const float* W_hh      = (const float*)d_in[5];
    const float* b_hh      = (const float*)d_in[6];
    const float* W_fc      = (const float*)d_in[7];
    const float* b_fc      = (const float*)d_in[8];
    const float* W_init_h  = (const float*)d_in[9];
    const float* b_init_h  = (const float*)d_in[10];
    const float* W_init_c  = (const float*)d_in[11];
    const float* b_init_c  = (const float*)d_in[12];
    float* out = (float*)d_out;

    float* ws = (float*)d_ws;
    float* h0 = ws;                 // 64*512
    float* h1 = ws + 32768;         // 64*512
    float* c  = ws + 65536;         // 64*512
    unsigned long long* keys = (unsigned long long*)(ws + 98304); // 2*64 packed keys

    init_kernel<<<64, 256, 0, stream>>>(enc, W_init_h, b_init_h, W_init_c, b_init_c,
                                        h0, c, out);
    for (int t = 0; t < MAXLEN - 1; ++t) {
        float* hin  = (t & 1) ? h1 : h0;
        float* hout = (t & 1) ? h0 : h1;
        unsigned long long* kread  = keys + (((t + 1) & 1) * 64); // buf[(t-1)&1]
        unsigned long long* kwrite = keys + ((t & 1) * 64);       // buf[t&1]
        lstm_step<<<256, 256, 0, stream>>>(emb, W_ih, b_ih, W_hh, b_hh, captions,
                                           kread, kwrite, hin, hout, c, t);
        fc_argmax<<<500, 256, 0, stream>>>(hout, W_fc, b_fc, out, kwrite, t);
    }
}